// Round 4
// baseline (256.517 us; speedup 1.0000x reference)
//
#include <hip/hip_runtime.h>
#include <math.h>

// B=4, L=1024, D=512, H=8, d=64
#define L_ 1024
#define D_ 512

typedef _Float16 half8 __attribute__((ext_vector_type(8)));
typedef _Float16 half4v __attribute__((ext_vector_type(4)));
typedef _Float16 half2v __attribute__((ext_vector_type(2)));
typedef float floatx4 __attribute__((ext_vector_type(4)));

#define QK_PITCH 136   // halves per (h,l) row in qk_ln staging (16B-aligned, bank-clean)

// ---------- prep: K,Q -> fp16 straight; V -> fp16 transposed Vt[b][h][d][m]
__global__ __launch_bounds__(256) void prep(
    const float* __restrict__ K, const float* __restrict__ Q,
    const float* __restrict__ V,
    _Float16* __restrict__ K16, _Float16* __restrict__ Q16,
    _Float16* __restrict__ Vt)
{
    __shared__ _Float16 tile[64][72];
    const int t = threadIdx.x;
    const int bi = blockIdx.x;
    if (bi < 2048) {
        #pragma unroll
        for (int it = 0; it < 2; ++it) {
            size_t f = (size_t)bi * 512 + it * 256 + t;
            const float4* src; _Float16* dst;
            if (f < 524288) { src = (const float4*)K; dst = K16; }
            else            { src = (const float4*)Q; dst = Q16; f -= 524288; }
            float4 v = src[f];
            half4v h = { (_Float16)v.x, (_Float16)v.y, (_Float16)v.z, (_Float16)v.w };
            *(half4v*)&dst[f * 4] = h;
        }
    } else {
        const int id = bi - 2048;           // 512 blocks: 4b x 8h x 16 mtiles
        const int mt = id & 15, h = (id >> 4) & 7, b = id >> 7;
        const float4* Vf4 = (const float4*)V;
        for (int it = 0; it < 4; ++it) {
            const int ml = (t >> 4) + 16 * it;
            const int c4 = t & 15;
            float4 v = Vf4[(size_t)(b * 1024 + mt * 64 + ml) * 128 + h * 16 + c4];
            tile[c4 * 4 + 0][ml] = (_Float16)v.x;
            tile[c4 * 4 + 1][ml] = (_Float16)v.y;
            tile[c4 * 4 + 2][ml] = (_Float16)v.z;
            tile[c4 * 4 + 3][ml] = (_Float16)v.w;
        }
        __syncthreads();
        const int d = t >> 2, seg = t & 3;
        half8 o0 = *(half8*)&tile[d][seg * 16];
        half8 o1 = *(half8*)&tile[d][seg * 16 + 8];
        size_t obase = ((size_t)(b * 8 + h) * 64 + d) * 1024 + mt * 64 + seg * 16;
        *(half8*)&Vt[obase] = o0;
        *(half8*)&Vt[obase + 8] = o1;
    }
}

// ---------- qk_ln: e = exp(LN(K.Q^T) - M) via fp16 MFMA, masked, stored
// coalesced to flat S[b][h][l][m] via LDS staging. Round-1 structure
// (K-frags hoisted, 16B staged stores, conflict-free pitch) but the m-range
// is split 8 ways (128 m per block) so LDS drops to ~37 KB -> 4 blocks/CU
// (16 waves/CU, 2x the latency hiding). Row partial sums are reduced
// block-locally -> spart has 8 slots/row.
// M = max_h(2.8285*|gamma_h|+|beta_h|) is a data-independent LN output bound,
// so no per-row max pass is needed (exp never overflows).
__global__ __launch_bounds__(256, 4) void qk_ln(
    const _Float16* __restrict__ K16, const _Float16* __restrict__ Q16,
    const float* __restrict__ gamma, const float* __restrict__ beta,
    const float* __restrict__ doc,
    _Float16* __restrict__ S, float* __restrict__ spart)
{
    __shared__ _Float16 se[128 * QK_PITCH];   // 34,816 B
    __shared__ float sf[128][4];              //  2,048 B -> total 36.9 KB

    const int t  = threadIdx.x;
    const int bi = blockIdx.x;              // 2048 = 4b x 64 lt x 8 q
    const int b  = bi & 3;
    const int lt = (bi >> 2) & 63;
    const int q  = bi >> 8;                 // 0..7, 128 m each
    const int wv = t >> 6, lane = t & 63;
    const int col = lane & 15, quad = lane >> 4;
    const int len = (int)doc[b];
    const int lbase = lt * 16;

    float g[8], be[8], M = 0.f;
    #pragma unroll
    for (int h = 0; h < 8; ++h) {
        g[h] = gamma[h]; be[h] = beta[h];
        M = fmaxf(M, 2.8285f * fabsf(g[h]) + fabsf(be[h]));
    }

    const _Float16* Kb = K16 + (size_t)b * 524288;
    const _Float16* Qb = Q16 + (size_t)b * 524288;
    const size_t krow = (size_t)(lbase + col) * 512;

    half8 a0[8], a1[8];
    #pragma unroll
    for (int h = 0; h < 8; ++h) {
        a0[h] = *(const half8*)&Kb[krow + h * 64 + quad * 8];
        a1[h] = *(const half8*)&Kb[krow + h * 64 + 32 + quad * 8];
    }

    float sum[8][4];
    #pragma unroll
    for (int h = 0; h < 8; ++h)
        #pragma unroll
        for (int r = 0; r < 4; ++r) sum[h][r] = 0.f;

    #pragma unroll
    for (int mt = 0; mt < 2; ++mt) {
        const int m0 = q * 128 + wv * 32 + mt * 16;
        const size_t qrow = (size_t)(m0 + col) * 512;
        floatx4 c[8];
        #pragma unroll
        for (int h = 0; h < 8; ++h) {
            half8 b0 = *(const half8*)&Qb[qrow + h * 64 + quad * 8];
            half8 b1 = *(const half8*)&Qb[qrow + h * 64 + 32 + quad * 8];
            floatx4 z = {0.f, 0.f, 0.f, 0.f};
            z    = __builtin_amdgcn_mfma_f32_16x16x32_f16(a0[h], b0, z, 0, 0, 0);
            c[h] = __builtin_amdgcn_mfma_f32_16x16x32_f16(a1[h], b1, z, 0, 0, 0);
        }
        const bool mok = (m0 + col) < len;
        #pragma unroll
        for (int r = 0; r < 4; ++r) {
            const int l = lbase + quad * 4 + r;
            float mu = 0.f;
            #pragma unroll
            for (int h = 0; h < 8; ++h) mu += c[h][r];
            mu *= 0.125f;
            float var = 0.f;
            #pragma unroll
            for (int h = 0; h < 8; ++h) { float dd = c[h][r] - mu; var += dd * dd; }
            var *= 0.125f;
            const float rs = 1.0f / sqrtf(var + 1e-5f);
            const bool keep = mok && (l < len);
            #pragma unroll
            for (int h = 0; h < 8; ++h) {
                float e = 0.f;
                if (keep) {
                    float val = (c[h][r] - mu) * rs * g[h] + be[h];
                    e = __expf(val - M);
                }
                sum[h][r] += e;
                se[(h * 16 + quad * 4 + r) * QK_PITCH + wv * 32 + mt * 16 + col] =
                    (_Float16)e;
            }
        }
    }

    // reduce row partial sums over the 16 col-lanes of each quad; stash in sf
    #pragma unroll
    for (int h = 0; h < 8; ++h)
        #pragma unroll
        for (int r = 0; r < 4; ++r) {
            float s = sum[h][r];
            s += __shfl_xor(s, 1); s += __shfl_xor(s, 2);
            s += __shfl_xor(s, 4); s += __shfl_xor(s, 8);
            sum[h][r] = s;
        }
    if (col == 0) {
        #pragma unroll
        for (int h = 0; h < 8; ++h)
            #pragma unroll
            for (int r = 0; r < 4; ++r)
                sf[h * 16 + quad * 4 + r][wv] = sum[h][r];
    }
    __syncthreads();

    // coalesced store: 128 rows x 256 B
    #pragma unroll
    for (int it = 0; it < 8; ++it) {
        const int row = it * 16 + (t >> 4);
        const int h = row >> 4, l = row & 15;
        half8 v = *(half8*)&se[row * QK_PITCH + (t & 15) * 8];
        *(half8*)&S[((size_t)((b * 8 + h) * 1024 + lbase + l)) * 1024
                    + q * 128 + (t & 15) * 8] = v;
    }

    // block-local wave reduction -> one spart slot per (row, q)
    if (t < 128) {
        const float s = sf[t][0] + sf[t][1] + sf[t][2] + sf[t][3];
        const int h = t >> 4, ll = t & 15;
        spart[((size_t)((b * 8 + h) * 1024 + lbase + ll)) * 8 + q] = s;
    }
}

// ---------- stats_reduce: inv[row] = 1/sum(e) (0 for padded rows)
__global__ __launch_bounds__(256) void stats_reduce(
    const float* __restrict__ spart, const float* __restrict__ doc,
    float* __restrict__ inv)
{
    const int i = blockIdx.x * 256 + threadIdx.x;   // 32768 rows
    const int l = i & 1023;
    const int b = i >> 13;
    const int len = (int)doc[b];
    float s = 0.f;
    #pragma unroll
    for (int j = 0; j < 8; ++j) s += spart[(size_t)i * 8 + j];
    inv[i] = (l < len && s > 0.f) ? 1.0f / s : 0.f;
}

// ---------- pv: pure streaming PV MFMA on raw fp16 e; normalization (inv)
// applied to the fp32 accumulator in the epilogue. No LDS, no shuffles,
// no atomics. 8-deep register ring prefetch; Vt L2-resident.
__global__ __launch_bounds__(256) void pv(
    const _Float16* __restrict__ S, const _Float16* __restrict__ Vt,
    const float* __restrict__ invp,
    float* __restrict__ out)
{
    const int t = threadIdx.x, wv = t >> 6, lane = t & 63;
    const int col = lane & 15, quad = lane >> 4;
    const int bi = blockIdx.x;            // 512 = 4b x 8h x 16 lb
    const int lb = bi & 15, h = (bi >> 4) & 7, b = bi >> 7;
    const int l0 = lb * 64 + wv * 16;

    const _Float16* Arow = S + ((size_t)(b * 8 + h) * 1024 + l0 + col) * 1024;
    const _Float16* Vb = Vt + (size_t)(b * 8 + h) * 65536;

    floatx4 acc[4] = {{0,0,0,0},{0,0,0,0},{0,0,0,0},{0,0,0,0}};

    half8 ebuf[8];
    #pragma unroll
    for (int i = 0; i < 8; ++i)
        ebuf[i] = *(const half8*)&Arow[i * 32 + quad * 8];

    #pragma unroll
    for (int kc = 0; kc < 32; ++kc) {
        half8 a = ebuf[kc & 7];
        if (kc + 8 < 32)
            ebuf[kc & 7] = *(const half8*)&Arow[(kc + 8) * 32 + quad * 8];
        #pragma unroll
        for (int dt = 0; dt < 4; ++dt) {
            half8 bf = *(const half8*)&Vb[(size_t)(dt * 16 + col) * 1024
                                          + kc * 32 + quad * 8];
            acc[dt] = __builtin_amdgcn_mfma_f32_16x16x32_f16(a, bf, acc[dt], 0, 0, 0);
        }
    }

    #pragma unroll
    for (int r = 0; r < 4; ++r) {
        const int l = l0 + quad * 4 + r;
        const float ivr = invp[(size_t)(b * 8 + h) * 1024 + l];
        float* orow = out + (size_t)(b * 1024 + l) * 512 + h * 64;
        #pragma unroll
        for (int dt = 0; dt < 4; ++dt)
            orow[dt * 16 + col] = acc[dt][r] * ivr;
    }
}

// ---------- wsum: w column sums with m-major ownership.
// wacc[b][m] += sum_l e[l][m] * inv[l]  (summed over h via atomics).
// Coalesced: 256 threads x 8B = full 2KB row per iteration. Per-lane fp32
// register accumulation -> no cross-lane traffic at all. 1024 blocks
// (32 l's each) for latency hiding.
__global__ __launch_bounds__(256) void wsum(
    const _Float16* __restrict__ S, const float* __restrict__ invp,
    float* __restrict__ wacc)
{
    const int t = threadIdx.x;
    const int bi = blockIdx.x;            // 1024 = 4b x 8h x 32 lc
    const int lc = bi & 31, h = (bi >> 5) & 7, b = bi >> 8;
    const size_t rbase = (size_t)(b * 8 + h) * 1024 + lc * 32;
    const _Float16* Sb = S + rbase * 1024;
    const float* ivb = invp + rbase;
    const int m0 = t * 4;

    float a0 = 0.f, a1 = 0.f, a2 = 0.f, a3 = 0.f;
    #pragma unroll 8
    for (int l = 0; l < 32; ++l) {
        const float iv = ivb[l];
        half4v e = *(const half4v*)&Sb[(size_t)l * 1024 + m0];
        a0 += (float)e[0] * iv;
        a1 += (float)e[1] * iv;
        a2 += (float)e[2] * iv;
        a3 += (float)e[3] * iv;
    }
    float* wb = wacc + b * 1024 + m0;
    atomicAdd(&wb[0], a0);
    atomicAdd(&wb[1], a1);
    atomicAdd(&wb[2], a2);
    atomicAdd(&wb[3], a3);
}

// ---------- w finalize: w = softmax_m( (wacc/8)/len ), invalid -> 0
__global__ __launch_bounds__(256) void w_final(
    const float* __restrict__ wacc, const float* __restrict__ doc,
    float* __restrict__ wout)
{
    const int b = blockIdx.x;
    const int t = threadIdx.x;
    __shared__ float red[4];

    const float ds = doc[b];
    const int len = (int)ds;

    float v[4];
    float mx = -INFINITY;
    #pragma unroll
    for (int i = 0; i < 4; ++i) {
        const int m = t + 256 * i;
        const float raw = wacc[b * L_ + m];
        v[i] = (m < len) ? (raw * 0.125f) / ds : -INFINITY;
        mx = fmaxf(mx, v[i]);
    }
    #pragma unroll
    for (int off = 1; off < 64; off <<= 1) mx = fmaxf(mx, __shfl_xor(mx, off));
    if ((t & 63) == 0) red[t >> 6] = mx;
    __syncthreads();
    mx = fmaxf(fmaxf(red[0], red[1]), fmaxf(red[2], red[3]));

    float e[4];
    float sm = 0.f;
    #pragma unroll
    for (int i = 0; i < 4; ++i) {
        e[i] = (v[i] != -INFINITY) ? __expf(v[i] - mx) : 0.f;
        sm += e[i];
    }
    #pragma unroll
    for (int off = 1; off < 64; off <<= 1) sm += __shfl_xor(sm, off);
    __syncthreads();
    if ((t & 63) == 0) red[t >> 6] = sm;
    __syncthreads();
    sm = red[0] + red[1] + red[2] + red[3];
    const float inv = (sm > 0.f) ? 1.0f / sm : 0.f;

    #pragma unroll
    for (int i = 0; i < 4; ++i)
        wout[b * L_ + t + 256 * i] = e[i] * inv;
}

extern "C" void kernel_launch(void* const* d_in, const int* in_sizes, int n_in,
                              void* d_out, int out_size, void* d_ws, size_t ws_size,
                              hipStream_t stream)
{
    const float* K     = (const float*)d_in[0];
    const float* Q     = (const float*)d_in[1];
    const float* V     = (const float*)d_in[2];
    const float* doc   = (const float*)d_in[3];
    const float* gamma = (const float*)d_in[4];
    const float* beta  = (const float*)d_in[5];

    float* out  = (float*)d_out;
    float* wout = out + (size_t)4 * L_ * D_;

    _Float16* S    = (_Float16*)d_ws;               // 64 MB (e-values, flat)
    _Float16* K16  = S + (size_t)33554432;          // +4 MB
    _Float16* Q16  = K16 + 2097152;                 // +4 MB
    _Float16* Vt   = Q16 + 2097152;                 // +4 MB
    float*    spart = (float*)(Vt + 2097152);       // 1 MB used (32768 x 8)
    float*    invp  = spart + 524288;               // 128 KB
    float*    wacc  = invp + 32768;                 // 16 KB

    hipMemsetAsync(wacc, 0, 4096 * sizeof(float), stream);
    prep        <<<dim3(2560), dim3(256), 0, stream>>>(K, Q, V, K16, Q16, Vt);
    qk_ln       <<<dim3(2048), dim3(256), 0, stream>>>(K16, Q16, gamma, beta, doc, S, spart);
    stats_reduce<<<dim3(128),  dim3(256), 0, stream>>>(spart, doc, invp);
    pv          <<<dim3(512),  dim3(256), 0, stream>>>(S, Vt, invp, out);
    wsum        <<<dim3(1024), dim3(256), 0, stream>>>(S, invp, wacc);
    w_final     <<<dim3(4),    dim3(256), 0, stream>>>(wacc, doc, wout);
}

// Round 5
// 209.400 us; speedup vs baseline: 1.2250x; 1.2250x over previous
//
#include <hip/hip_runtime.h>
#include <math.h>

// B=4, L=1024, D=512, H=8, d=64
#define L_ 1024
#define D_ 512

typedef _Float16 half8 __attribute__((ext_vector_type(8)));
typedef _Float16 half4v __attribute__((ext_vector_type(4)));
typedef _Float16 half2v __attribute__((ext_vector_type(2)));
typedef float floatx4 __attribute__((ext_vector_type(4)));

#define LDS_PITCH 264   // halves per (h,l) row in qk_ln staging (16B-aligned, bank-skewed)

// ---------- prep: K,Q -> fp16 straight; V -> fp16 transposed Vt[b][h][d][m]
__global__ __launch_bounds__(256) void prep(
    const float* __restrict__ K, const float* __restrict__ Q,
    const float* __restrict__ V,
    _Float16* __restrict__ K16, _Float16* __restrict__ Q16,
    _Float16* __restrict__ Vt)
{
    __shared__ _Float16 tile[64][72];
    const int t = threadIdx.x;
    const int bi = blockIdx.x;
    if (bi < 512) {
        #pragma unroll
        for (int it = 0; it < 8; ++it) {
            size_t f = (size_t)bi * 2048 + it * 256 + t;
            const float4* src; _Float16* dst;
            if (f < 524288) { src = (const float4*)K; dst = K16; }
            else            { src = (const float4*)Q; dst = Q16; f -= 524288; }
            float4 v = src[f];
            half4v h = { (_Float16)v.x, (_Float16)v.y, (_Float16)v.z, (_Float16)v.w };
            *(half4v*)&dst[f * 4] = h;
        }
    } else {
        const int id = bi - 512;            // 512 blocks: 4b x 8h x 16 mtiles
        const int mt = id & 15, h = (id >> 4) & 7, b = id >> 7;
        const float4* Vf4 = (const float4*)V;
        for (int it = 0; it < 4; ++it) {
            const int ml = (t >> 4) + 16 * it;
            const int c4 = t & 15;
            float4 v = Vf4[(size_t)(b * 1024 + mt * 64 + ml) * 128 + h * 16 + c4];
            tile[c4 * 4 + 0][ml] = (_Float16)v.x;
            tile[c4 * 4 + 1][ml] = (_Float16)v.y;
            tile[c4 * 4 + 2][ml] = (_Float16)v.z;
            tile[c4 * 4 + 3][ml] = (_Float16)v.w;
        }
        __syncthreads();
        const int d = t >> 2, seg = t & 3;
        half8 o0 = *(half8*)&tile[d][seg * 16];
        half8 o1 = *(half8*)&tile[d][seg * 16 + 8];
        size_t obase = ((size_t)(b * 8 + h) * 64 + d) * 1024 + mt * 64 + seg * 16;
        *(half8*)&Vt[obase] = o0;
        *(half8*)&Vt[obase + 8] = o1;
    }
}

// ---------- qk_ln: e = exp(LN(K.Q^T) - M) via fp16 MFMA, masked, stored
// coalesced to S[b][h][l][m] via LDS; per-row partial sums -> spart.
// (Round-1 proven configuration: 54 us, 0 bank conflicts.)
// M = max_h(2.8285*|gamma_h|+|beta_h|) is a data-independent LN output bound,
// so no per-row max pass is needed (exp never overflows).
__global__ __launch_bounds__(256) void qk_ln(
    const _Float16* __restrict__ K16, const _Float16* __restrict__ Q16,
    const float* __restrict__ gamma, const float* __restrict__ beta,
    const float* __restrict__ doc,
    _Float16* __restrict__ S, float* __restrict__ spart)
{
    __shared__ _Float16 se[8 * 16 * LDS_PITCH];   // 67584 B -> 2 blocks/CU

    const int t  = threadIdx.x;
    const int bi = blockIdx.x;              // 1024 = 4b x 64 lt x 4 q
    const int b  = bi & 3;
    const int lt = (bi >> 2) & 63;
    const int q  = bi >> 8;
    const int wv = t >> 6, lane = t & 63;
    const int col = lane & 15, quad = lane >> 4;
    const int len = (int)doc[b];
    const int lbase = lt * 16;

    float g[8], be[8], M = 0.f;
    #pragma unroll
    for (int h = 0; h < 8; ++h) {
        g[h] = gamma[h]; be[h] = beta[h];
        M = fmaxf(M, 2.8285f * fabsf(g[h]) + fabsf(be[h]));
    }

    const _Float16* Kb = K16 + (size_t)b * 524288;
    const _Float16* Qb = Q16 + (size_t)b * 524288;
    const size_t krow = (size_t)(lbase + col) * 512;

    half8 a0[8], a1[8];
    #pragma unroll
    for (int h = 0; h < 8; ++h) {
        a0[h] = *(const half8*)&Kb[krow + h * 64 + quad * 8];
        a1[h] = *(const half8*)&Kb[krow + h * 64 + 32 + quad * 8];
    }

    float sum[8][4];
    #pragma unroll
    for (int h = 0; h < 8; ++h)
        #pragma unroll
        for (int r = 0; r < 4; ++r) sum[h][r] = 0.f;

    for (int mt = 0; mt < 4; ++mt) {
        const int m0 = q * 256 + wv * 64 + mt * 16;
        const size_t qrow = (size_t)(m0 + col) * 512;
        floatx4 c[8];
        #pragma unroll
        for (int h = 0; h < 8; ++h) {
            half8 b0 = *(const half8*)&Qb[qrow + h * 64 + quad * 8];
            half8 b1 = *(const half8*)&Qb[qrow + h * 64 + 32 + quad * 8];
            floatx4 z = {0.f, 0.f, 0.f, 0.f};
            z    = __builtin_amdgcn_mfma_f32_16x16x32_f16(a0[h], b0, z, 0, 0, 0);
            c[h] = __builtin_amdgcn_mfma_f32_16x16x32_f16(a1[h], b1, z, 0, 0, 0);
        }
        const bool mok = (m0 + col) < len;
        #pragma unroll
        for (int r = 0; r < 4; ++r) {
            const int l = lbase + quad * 4 + r;
            float mu = 0.f;
            #pragma unroll
            for (int h = 0; h < 8; ++h) mu += c[h][r];
            mu *= 0.125f;
            float var = 0.f;
            #pragma unroll
            for (int h = 0; h < 8; ++h) { float dd = c[h][r] - mu; var += dd * dd; }
            var *= 0.125f;
            const float rs = 1.0f / sqrtf(var + 1e-5f);
            const bool keep = mok && (l < len);
            #pragma unroll
            for (int h = 0; h < 8; ++h) {
                float e = 0.f;
                if (keep) {
                    float val = (c[h][r] - mu) * rs * g[h] + be[h];
                    e = __expf(val - M);
                }
                sum[h][r] += e;
                se[(h * 16 + quad * 4 + r) * LDS_PITCH + wv * 64 + mt * 16 + col] =
                    (_Float16)e;
            }
        }
    }

    // reduce row partial sums over the 16 col-lanes of each quad
    #pragma unroll
    for (int h = 0; h < 8; ++h)
        #pragma unroll
        for (int r = 0; r < 4; ++r) {
            float s = sum[h][r];
            s += __shfl_xor(s, 1); s += __shfl_xor(s, 2);
            s += __shfl_xor(s, 4); s += __shfl_xor(s, 8);
            sum[h][r] = s;
        }
    if (col == 0) {
        #pragma unroll
        for (int h = 0; h < 8; ++h)
            #pragma unroll
            for (int r = 0; r < 4; ++r)
                spart[((size_t)((b * 8 + h) * 1024 + lbase + quad * 4 + r)) * 16
                      + q * 4 + wv] = sum[h][r];
    }
    __syncthreads();

    // coalesced store: 128 rows x 512 B
    for (int it = 0; it < 16; ++it) {
        const int rr = it * 8 + (t >> 5);
        const int h = rr >> 4, l = rr & 15;
        half8 v = *(half8*)&se[rr * LDS_PITCH + (t & 31) * 8];
        *(half8*)&S[((size_t)((b * 8 + h) * 1024 + lbase + l)) * 1024
                    + q * 256 + (t & 31) * 8] = v;
    }
}

// ---------- stats_reduce: inv[row] = 1/sum(e) (0 for padded rows)
__global__ __launch_bounds__(256) void stats_reduce(
    const float* __restrict__ spart, const float* __restrict__ doc,
    float* __restrict__ inv)
{
    const int i = blockIdx.x * 256 + threadIdx.x;   // 32768 rows
    const int l = i & 1023;
    const int b = i >> 13;
    const int len = (int)doc[b];
    float s = 0.f;
    #pragma unroll
    for (int j = 0; j < 16; ++j) s += spart[(size_t)i * 16 + j];
    inv[i] = (l < len && s > 0.f) ? 1.0f / s : 0.f;
}

// ---------- pv: pure streaming PV MFMA on raw fp16 e; normalization (inv)
// applied to the fp32 accumulator in the epilogue. No LDS, no shuffles,
// no atomics. 8-deep register ring prefetch on the HBM-streamed e rows;
// ping-pong 1-ahead prefetch on the L2-resident Vt rows (breaks the
// load->mfma serial dependency that exposed L2 latency every kc).
__global__ __launch_bounds__(256) void pv(
    const _Float16* __restrict__ S, const _Float16* __restrict__ Vt,
    const float* __restrict__ invp,
    float* __restrict__ out)
{
    const int t = threadIdx.x, wv = t >> 6, lane = t & 63;
    const int col = lane & 15, quad = lane >> 4;
    const int bi = blockIdx.x;            // 512 = 4b x 8h x 16 lb
    const int lb = bi & 15, h = (bi >> 4) & 7, b = bi >> 7;
    const int l0 = lb * 64 + wv * 16;

    const _Float16* Arow = S + ((size_t)(b * 8 + h) * 1024 + l0 + col) * 1024;
    const _Float16* Vb = Vt + (size_t)(b * 8 + h) * 65536 + (size_t)col * 1024
                       + quad * 8;

    floatx4 acc[4] = {{0,0,0,0},{0,0,0,0},{0,0,0,0},{0,0,0,0}};

    half8 ebuf[8];
    #pragma unroll
    for (int i = 0; i < 8; ++i)
        ebuf[i] = *(const half8*)&Arow[i * 32 + quad * 8];

    half8 va[4], vb[4];
    #pragma unroll
    for (int dt = 0; dt < 4; ++dt)
        va[dt] = *(const half8*)&Vb[(size_t)(dt * 16) * 1024];

    #pragma unroll
    for (int kc = 0; kc < 32; kc += 2) {
        // even step: consume va, prefetch vb (kc+1)
        half8 ae = ebuf[kc & 7];
        if (kc + 8 < 32)
            ebuf[kc & 7] = *(const half8*)&Arow[(kc + 8) * 32 + quad * 8];
        #pragma unroll
        for (int dt = 0; dt < 4; ++dt)
            vb[dt] = *(const half8*)&Vb[(size_t)(dt * 16) * 1024 + (kc + 1) * 32];
        #pragma unroll
        for (int dt = 0; dt < 4; ++dt)
            acc[dt] = __builtin_amdgcn_mfma_f32_16x16x32_f16(ae, va[dt], acc[dt], 0, 0, 0);

        // odd step: consume vb, prefetch va (kc+2)
        half8 ao = ebuf[(kc + 1) & 7];
        if (kc + 9 < 32)
            ebuf[(kc + 1) & 7] = *(const half8*)&Arow[(kc + 9) * 32 + quad * 8];
        if (kc + 2 < 32) {
            #pragma unroll
            for (int dt = 0; dt < 4; ++dt)
                va[dt] = *(const half8*)&Vb[(size_t)(dt * 16) * 1024 + (kc + 2) * 32];
        }
        #pragma unroll
        for (int dt = 0; dt < 4; ++dt)
            acc[dt] = __builtin_amdgcn_mfma_f32_16x16x32_f16(ao, vb[dt], acc[dt], 0, 0, 0);
    }

    #pragma unroll
    for (int r = 0; r < 4; ++r) {
        const int l = l0 + quad * 4 + r;
        const float ivr = invp[(size_t)(b * 8 + h) * 1024 + l];
        float* orow = out + (size_t)(b * 1024 + l) * 512 + h * 64;
        #pragma unroll
        for (int dt = 0; dt < 4; ++dt)
            orow[dt * 16 + col] = acc[dt][r] * ivr;
    }
}

// ---------- wsum: w column sums with m-major ownership.
// wacc[b][m] += sum_l e[l][m] * inv[l]  (summed over h via atomics).
// 16B half8 loads (fully coalesced 1KB/wave), 8 fp32 accumulators per
// thread, 4x unroll -> >=4 half8 loads in flight per lane. Block-local
// LDS combine keeps global atomics at 4 per thread.
__global__ __launch_bounds__(256) void wsum(
    const _Float16* __restrict__ S, const float* __restrict__ invp,
    float* __restrict__ wacc)
{
    __shared__ float ws[1024];
    const int t = threadIdx.x;
    const int bi = blockIdx.x;            // 512 = 4b x 8h x 16 slab(64 l)
    const int lc = bi & 15, h = (bi >> 4) & 7, b = bi >> 7;
    const size_t rbase = (size_t)(b * 8 + h) * 1024 + lc * 64;
    const _Float16* Sb = S + rbase * 1024;
    const float* ivb = invp + rbase;
    const int mi = (t & 127) * 8;         // 8 m's per thread
    const int lp = t >> 7;                // l parity (0/1)

    float acc[8];
    #pragma unroll
    for (int j = 0; j < 8; ++j) acc[j] = 0.f;

    #pragma unroll 4
    for (int l = lp; l < 64; l += 2) {
        const float iv = ivb[l];
        half8 e = *(const half8*)&Sb[(size_t)l * 1024 + mi];
        #pragma unroll
        for (int j = 0; j < 8; ++j) acc[j] += (float)e[j] * iv;
    }

    if (lp == 0) {
        #pragma unroll
        for (int j = 0; j < 8; ++j) ws[mi + j] = acc[j];
    }
    __syncthreads();
    if (lp == 1) {
        #pragma unroll
        for (int j = 0; j < 8; ++j) ws[mi + j] += acc[j];
    }
    __syncthreads();

    float* wb = wacc + b * 1024;
    #pragma unroll
    for (int i = 0; i < 4; ++i)
        atomicAdd(&wb[t * 4 + i], ws[t * 4 + i]);
}

// ---------- w finalize: w = softmax_m( (wacc/8)/len ), invalid -> 0
__global__ __launch_bounds__(256) void w_final(
    const float* __restrict__ wacc, const float* __restrict__ doc,
    float* __restrict__ wout)
{
    const int b = blockIdx.x;
    const int t = threadIdx.x;
    __shared__ float red[4];

    const float ds = doc[b];
    const int len = (int)ds;

    float v[4];
    float mx = -INFINITY;
    #pragma unroll
    for (int i = 0; i < 4; ++i) {
        const int m = t + 256 * i;
        const float raw = wacc[b * L_ + m];
        v[i] = (m < len) ? (raw * 0.125f) / ds : -INFINITY;
        mx = fmaxf(mx, v[i]);
    }
    #pragma unroll
    for (int off = 1; off < 64; off <<= 1) mx = fmaxf(mx, __shfl_xor(mx, off));
    if ((t & 63) == 0) red[t >> 6] = mx;
    __syncthreads();
    mx = fmaxf(fmaxf(red[0], red[1]), fmaxf(red[2], red[3]));

    float e[4];
    float sm = 0.f;
    #pragma unroll
    for (int i = 0; i < 4; ++i) {
        e[i] = (v[i] != -INFINITY) ? __expf(v[i] - mx) : 0.f;
        sm += e[i];
    }
    #pragma unroll
    for (int off = 1; off < 64; off <<= 1) sm += __shfl_xor(sm, off);
    __syncthreads();
    if ((t & 63) == 0) red[t >> 6] = sm;
    __syncthreads();
    sm = red[0] + red[1] + red[2] + red[3];
    const float inv = (sm > 0.f) ? 1.0f / sm : 0.f;

    #pragma unroll
    for (int i = 0; i < 4; ++i)
        wout[b * L_ + t + 256 * i] = e[i] * inv;
}

extern "C" void kernel_launch(void* const* d_in, const int* in_sizes, int n_in,
                              void* d_out, int out_size, void* d_ws, size_t ws_size,
                              hipStream_t stream)
{
    const float* K     = (const float*)d_in[0];
    const float* Q     = (const float*)d_in[1];
    const float* V     = (const float*)d_in[2];
    const float* doc   = (const float*)d_in[3];
    const float* gamma = (const float*)d_in[4];
    const float* beta  = (const float*)d_in[5];

    float* out  = (float*)d_out;
    float* wout = out + (size_t)4 * L_ * D_;

    _Float16* S    = (_Float16*)d_ws;               // 64 MB (e-values, flat)
    _Float16* K16  = S + (size_t)33554432;          // +4 MB
    _Float16* Q16  = K16 + 2097152;                 // +4 MB
    _Float16* Vt   = Q16 + 2097152;                 // +4 MB
    float*    spart = (float*)(Vt + 2097152);       // 2 MB (32768 x 16)
    float*    invp  = spart + 524288;               // 128 KB
    float*    wacc  = invp + 32768;                 // 16 KB

    hipMemsetAsync(wacc, 0, 4096 * sizeof(float), stream);
    prep        <<<dim3(1024), dim3(256), 0, stream>>>(K, Q, V, K16, Q16, Vt);
    qk_ln       <<<dim3(1024), dim3(256), 0, stream>>>(K16, Q16, gamma, beta, doc, S, spart);
    stats_reduce<<<dim3(128),  dim3(256), 0, stream>>>(spart, doc, invp);
    pv          <<<dim3(512),  dim3(256), 0, stream>>>(S, Vt, invp, out);
    wsum        <<<dim3(512),  dim3(256), 0, stream>>>(S, invp, wacc);
    w_final     <<<dim3(4),    dim3(256), 0, stream>>>(wacc, doc, wout);
}